// Round 1
// baseline (55.380 us; speedup 1.0000x reference)
//
#include <hip/hip_runtime.h>
#include <hip/hip_bf16.h>
#include <math.h>

// Quanvolution collapses analytically:
//   per patch p (9 pixels x_j, row-major 3x3), z_j = cos(w_j)*cos(pi*x_j)
//   ev0 = z1*z2*...*z8 ; ev1 = z0*z1 ; ev2 = z0*z1*z2 ; ev3 = z0*z1*z2*z3
//   out[h][w][f] = sum_c ev_f(patch(c,h,w)), flat layout [94][94][4]
// (Heisenberg propagation of Z_j through the CNOT ring of BasicEntanglerLayers;
//  RX layer keeps the product state, so expvals factorize.)

#define KS   3
#define FOUT 4
#define HIN  96
#define HOUT 94
#define CIN  3

__global__ __launch_bounds__(256) void quanv_kernel(const float* __restrict__ x,
                                                    const float* __restrict__ w,
                                                    float* __restrict__ out) {
    int idx = blockIdx.x * blockDim.x + threadIdx.x;
    if (idx >= HOUT * HOUT) return;
    int h  = idx / HOUT;
    int wc = idx % HOUT;

    // cos of RX weights (9 scalars, every thread computes; trivial)
    float cw[9];
#pragma unroll
    for (int j = 0; j < 9; ++j) cw[j] = __cosf(w[j]);
    const float W1 = cw[0] * cw[1];
    const float W2 = W1 * cw[2];
    const float W3 = W2 * cw[3];
    const float W0 = cw[1] * cw[2] * cw[3] * cw[4] * cw[5] * cw[6] * cw[7] * cw[8];

    const float PI = 3.14159265358979323846f;
    float acc0 = 0.f, acc1 = 0.f, acc2 = 0.f, acc3 = 0.f;

#pragma unroll
    for (int c = 0; c < CIN; ++c) {
        const float* xc = x + c * HIN * HIN;
        float p[9];
#pragma unroll
        for (int kr = 0; kr < KS; ++kr) {
#pragma unroll
            for (int kc = 0; kc < KS; ++kc) {
                p[kr * KS + kc] = __cosf(PI * xc[(h + kr) * HIN + (wc + kc)]);
            }
        }
        const float pr01   = p[0] * p[1];
        const float pr012  = pr01 * p[2];
        const float pr0123 = pr012 * p[3];
        const float pr18   = p[1] * p[2] * p[3] * p[4] * p[5] * p[6] * p[7] * p[8];
        acc0 += W0 * pr18;
        acc1 += W1 * pr01;
        acc2 += W2 * pr012;
        acc3 += W3 * pr0123;
    }

    reinterpret_cast<float4*>(out)[idx] = make_float4(acc0, acc1, acc2, acc3);
}

extern "C" void kernel_launch(void* const* d_in, const int* in_sizes, int n_in,
                              void* d_out, int out_size, void* d_ws, size_t ws_size,
                              hipStream_t stream) {
    const float* x = (const float*)d_in[0];     // [1,3,96,96] fp32
    const float* w = (const float*)d_in[1];     // [1,9] fp32
    float* out = (float*)d_out;                 // [1,4,94,94] fp32 (flat = [94][94][4])

    const int n = HOUT * HOUT;
    dim3 block(256);
    dim3 grid((n + 255) / 256);
    hipLaunchKernelGGL(quanv_kernel, grid, block, 0, stream, x, w, out);
}